// Round 4
// baseline (1665.839 us; speedup 1.0000x reference)
//
#include <hip/hip_runtime.h>
#include <hip/hip_bf16.h>

// Problem constants (MoE grouped FFN, uniform groups)
#define NE 32      // experts
#define HD 2048    // hidden
#define ID 1024    // intermediate
#define GT 1024    // tokens per expert (T/E = 32768/32)

// Tile config
#define BM 128
#define BN 128
#define BK 64

typedef __attribute__((ext_vector_type(8))) __bf16 bf16x8;
typedef __attribute__((ext_vector_type(4))) float  f32x4;

__device__ __forceinline__ __bf16 f2b(float f) { return (__bf16)f; }

__device__ __forceinline__ bf16x8 pack8(const f32x4 a, const f32x4 b) {
  bf16x8 v;
  v[0] = f2b(a[0]); v[1] = f2b(a[1]); v[2] = f2b(a[2]); v[3] = f2b(a[3]);
  v[4] = f2b(b[0]); v[5] = f2b(b[1]); v[6] = f2b(b[2]); v[7] = f2b(b[3]);
  return v;
}

// ---------------------------------------------------------------------------
// Kernel 1: gate_up = x_e @ w13_e ; h = silu(gate)*up  (bf16 out to ws)
// grid (ID/BN=8, GT/BM=8, NE=32), 256 threads (4 waves 2x2).
// T14 pipeline: issue tile-(k+1) global loads into regs BEFORE tile-k MFMA;
// cvt+ds_write at top of next iter. Tail barrier = lgkmcnt(0)+s_barrier
// (no vmcnt drain -> prefetch loads stay in flight across the barrier).
// LDS XOR swizzle (R2/R3-verified):
//   A:  As[row][(oct ^ (row&7))*8 + j]
//   B:  Bg/Bu[row][(oct ^ ((row>>1)&7))*8 + j]
// ---------------------------------------------------------------------------
__global__ __launch_bounds__(256, 2)
void moe_gemm1_swiglu(const float* __restrict__ x,
                      const float* __restrict__ w13,
                      __bf16* __restrict__ h) {
  __shared__ __bf16 As[BM][BK];
  __shared__ __bf16 Bg[BN][BK];
  __shared__ __bf16 Bu[BN][BK];

  const int t  = threadIdx.x;
  const int e  = blockIdx.z;
  const int m0 = blockIdx.y * BM;
  const int n0 = blockIdx.x * BN;

  const float* xA = x   + (size_t)(e * GT + m0) * HD;
  const float* wB = w13 + (size_t)e * HD * (2 * ID);

  const int wid = t >> 6, lane = t & 63;
  const int wm = wid >> 1, wn = wid & 1;
  const int fr = lane & 15, fq = lane >> 4;

  // staging ownership
  const int nq = t & 31;        // n-quad 0..31 (4 cols)
  const int ko = t >> 5;        // k-octet 0..7 (8 k-rows)

  f32x4 accg[4][4];
  f32x4 accu[4][4];
#pragma unroll
  for (int i = 0; i < 4; ++i)
#pragma unroll
    for (int j = 0; j < 4; ++j) { accg[i][j] = 0.f; accu[i][j] = 0.f; }

  // prefetch registers
  f32x4 ra[4][2];
  f32x4 rg[8], ru[8];

#define LOAD_TILE1(K0)                                                         \
  do {                                                                         \
    _Pragma("unroll")                                                          \
    for (int i = 0; i < 4; ++i) {                                              \
      int id = i * 256 + t;                                                    \
      int r = id >> 3, oc = id & 7;                                            \
      const float* src = xA + (size_t)r * HD + (K0) + oc * 8;                  \
      ra[i][0] = *reinterpret_cast<const f32x4*>(src);                         \
      ra[i][1] = *reinterpret_cast<const f32x4*>(src + 4);                     \
    }                                                                          \
    const float* pg = wB + (size_t)((K0) + ko * 8) * (2 * ID) + (n0 + nq * 4); \
    _Pragma("unroll")                                                          \
    for (int j = 0; j < 8; ++j)                                                \
      rg[j] = *reinterpret_cast<const f32x4*>(pg + (size_t)j * (2 * ID));      \
    const float* pu = pg + ID;                                                 \
    _Pragma("unroll")                                                          \
    for (int j = 0; j < 8; ++j)                                                \
      ru[j] = *reinterpret_cast<const f32x4*>(pu + (size_t)j * (2 * ID));      \
  } while (0)

  LOAD_TILE1(0);

  for (int k0 = 0; k0 < HD; k0 += BK) {
    // ---- cvt + ds_write (consumes prefetched regs; vmcnt waits auto) ----
#pragma unroll
    for (int i = 0; i < 4; ++i) {
      int id = i * 256 + t;
      int r = id >> 3, oc = id & 7;
      *reinterpret_cast<bf16x8*>(&As[r][(oc ^ (r & 7)) * 8]) = pack8(ra[i][0], ra[i][1]);
    }
#pragma unroll
    for (int c = 0; c < 4; ++c) {
      int row = nq * 4 + c;
      int slot = (ko ^ ((row >> 1) & 7)) * 8;
      bf16x8 vg, vu;
#pragma unroll
      for (int j = 0; j < 8; ++j) { vg[j] = f2b(rg[j][c]); vu[j] = f2b(ru[j][c]); }
      *reinterpret_cast<bf16x8*>(&Bg[row][slot]) = vg;
      *reinterpret_cast<bf16x8*>(&Bu[row][slot]) = vu;
    }
    __syncthreads();

    // ---- issue next tile's global loads (latency hides under MFMA) ----
    if (k0 + BK < HD) LOAD_TILE1(k0 + BK);

    // ---- MFMA on tile k0 ----
    __builtin_amdgcn_s_setprio(1);
#pragma unroll
    for (int kk = 0; kk < BK; kk += 32) {
      const int kb = kk >> 3;   // 0 or 4
      bf16x8 af[4], bgf[4], buf2[4];
#pragma unroll
      for (int mi = 0; mi < 4; ++mi) {
        int row = wm * 64 + mi * 16 + fr;
        int oct = (fq + kb) ^ (row & 7);
        af[mi] = *reinterpret_cast<const bf16x8*>(&As[row][oct * 8]);
      }
#pragma unroll
      for (int ni = 0; ni < 4; ++ni) {
        int row = wn * 64 + ni * 16 + fr;
        int oct = (fq + kb) ^ ((row >> 1) & 7);
        bgf[ni]  = *reinterpret_cast<const bf16x8*>(&Bg[row][oct * 8]);
        buf2[ni] = *reinterpret_cast<const bf16x8*>(&Bu[row][oct * 8]);
      }
#pragma unroll
      for (int mi = 0; mi < 4; ++mi)
#pragma unroll
        for (int ni = 0; ni < 4; ++ni) {
          accg[mi][ni] = __builtin_amdgcn_mfma_f32_16x16x32_bf16(af[mi], bgf[ni], accg[mi][ni], 0, 0, 0);
          accu[mi][ni] = __builtin_amdgcn_mfma_f32_16x16x32_bf16(af[mi], buf2[ni], accu[mi][ni], 0, 0, 0);
        }
    }
    __builtin_amdgcn_s_setprio(0);

    // ---- tail barrier WITHOUT vmcnt drain ----
    asm volatile("s_waitcnt lgkmcnt(0)" ::: "memory");
    __builtin_amdgcn_s_barrier();
  }
#undef LOAD_TILE1

  // ---- epilogue: SwiGLU, write h (bf16) ----
#pragma unroll
  for (int mi = 0; mi < 4; ++mi)
#pragma unroll
    for (int ni = 0; ni < 4; ++ni)
#pragma unroll
      for (int j = 0; j < 4; ++j) {
        int row = m0 + wm * 64 + mi * 16 + fq * 4 + j;
        int col = n0 + wn * 64 + ni * 16 + fr;
        float g = accg[mi][ni][j];
        float u = accu[mi][ni][j];
        float s = g / (1.f + __expf(-g));
        h[(size_t)(e * GT + row) * ID + col] = f2b(s * u);
      }
}

// ---------------------------------------------------------------------------
// Kernel 2: out = h @ w2_e   (h bf16 [T][I], w2 f32 [E][I][H], out f32)
// grid (HD/BN=16, GT/BM=8, NE=32), 256 threads. Same T14 pipeline.
// ---------------------------------------------------------------------------
__global__ __launch_bounds__(256, 2)
void moe_gemm2(const __bf16* __restrict__ h,
               const float* __restrict__ w2,
               float* __restrict__ out) {
  __shared__ __bf16 As[BM][BK];
  __shared__ __bf16 Bs[BN][BK];

  const int t  = threadIdx.x;
  const int e  = blockIdx.z;
  const int m0 = blockIdx.y * BM;
  const int n0 = blockIdx.x * BN;

  const __bf16* hA = h  + (size_t)(e * GT + m0) * ID;
  const float*  wB = w2 + (size_t)e * ID * HD;

  const int wid = t >> 6, lane = t & 63;
  const int wm = wid >> 1, wn = wid & 1;
  const int fr = lane & 15, fq = lane >> 4;

  const int nq = t & 31;
  const int ko = t >> 5;

  f32x4 acc[4][4];
#pragma unroll
  for (int i = 0; i < 4; ++i)
#pragma unroll
    for (int j = 0; j < 4; ++j) acc[i][j] = 0.f;

  bf16x8 raa[4];
  f32x4 rb[8];

#define LOAD_TILE2(K0)                                                         \
  do {                                                                         \
    _Pragma("unroll")                                                          \
    for (int i = 0; i < 4; ++i) {                                              \
      int id = i * 256 + t;                                                    \
      int koA = id & 7, m = id >> 3;                                           \
      raa[i] = *reinterpret_cast<const bf16x8*>(hA + (size_t)m * ID + (K0) + koA * 8); \
    }                                                                          \
    const float* pg = wB + (size_t)((K0) + ko * 8) * HD + (n0 + nq * 4);       \
    _Pragma("unroll")                                                          \
    for (int j = 0; j < 8; ++j)                                                \
      rb[j] = *reinterpret_cast<const f32x4*>(pg + (size_t)j * HD);            \
  } while (0)

  LOAD_TILE2(0);

  for (int k0 = 0; k0 < ID; k0 += BK) {
    // ---- ds_write from regs ----
#pragma unroll
    for (int i = 0; i < 4; ++i) {
      int id = i * 256 + t;
      int koA = id & 7, m = id >> 3;
      *reinterpret_cast<bf16x8*>(&As[m][(koA ^ (m & 7)) * 8]) = raa[i];
    }
#pragma unroll
    for (int c = 0; c < 4; ++c) {
      int row = nq * 4 + c;
      int slot = (ko ^ ((row >> 1) & 7)) * 8;
      bf16x8 v;
#pragma unroll
      for (int j = 0; j < 8; ++j) v[j] = f2b(rb[j][c]);
      *reinterpret_cast<bf16x8*>(&Bs[row][slot]) = v;
    }
    __syncthreads();

    // ---- issue next tile's loads ----
    if (k0 + BK < ID) LOAD_TILE2(k0 + BK);

    // ---- MFMA ----
    __builtin_amdgcn_s_setprio(1);
#pragma unroll
    for (int kk = 0; kk < BK; kk += 32) {
      const int kb = kk >> 3;
      bf16x8 af[4], bf[4];
#pragma unroll
      for (int mi = 0; mi < 4; ++mi) {
        int row = wm * 64 + mi * 16 + fr;
        int oct = (fq + kb) ^ (row & 7);
        af[mi] = *reinterpret_cast<const bf16x8*>(&As[row][oct * 8]);
      }
#pragma unroll
      for (int ni = 0; ni < 4; ++ni) {
        int row = wn * 64 + ni * 16 + fr;
        int oct = (fq + kb) ^ ((row >> 1) & 7);
        bf[ni] = *reinterpret_cast<const bf16x8*>(&Bs[row][oct * 8]);
      }
#pragma unroll
      for (int mi = 0; mi < 4; ++mi)
#pragma unroll
        for (int ni = 0; ni < 4; ++ni)
          acc[mi][ni] = __builtin_amdgcn_mfma_f32_16x16x32_bf16(af[mi], bf[ni], acc[mi][ni], 0, 0, 0);
    }
    __builtin_amdgcn_s_setprio(0);

    asm volatile("s_waitcnt lgkmcnt(0)" ::: "memory");
    __builtin_amdgcn_s_barrier();
  }
#undef LOAD_TILE2

  // ---- epilogue: f32 store ----
#pragma unroll
  for (int mi = 0; mi < 4; ++mi)
#pragma unroll
    for (int ni = 0; ni < 4; ++ni)
#pragma unroll
      for (int j = 0; j < 4; ++j) {
        int row = m0 + wm * 64 + mi * 16 + fq * 4 + j;
        int col = n0 + wn * 64 + ni * 16 + fr;
        out[(size_t)(e * GT + row) * HD + col] = acc[mi][ni][j];
      }
}

extern "C" void kernel_launch(void* const* d_in, const int* in_sizes, int n_in,
                              void* d_out, int out_size, void* d_ws, size_t ws_size,
                              hipStream_t stream) {
  const float* x   = (const float*)d_in[0];
  const float* w13 = (const float*)d_in[1];
  const float* w2  = (const float*)d_in[2];
  float* out = (float*)d_out;
  __bf16* h = (__bf16*)d_ws;   // T x I bf16 = 64 MiB scratch

  moe_gemm1_swiglu<<<dim3(ID / BN, GT / BM, NE), dim3(256), 0, stream>>>(x, w13, h);
  moe_gemm2<<<dim3(HD / BN, GT / BM, NE), dim3(256), 0, stream>>>(h, w2, out);
}

// Round 5
// 824.763 us; speedup vs baseline: 2.0198x; 2.0198x over previous
//
#include <hip/hip_runtime.h>
#include <hip/hip_bf16.h>

// Problem constants (MoE grouped FFN, uniform groups)
#define NE 32      // experts
#define HD 2048    // hidden
#define ID 1024    // intermediate
#define GT 1024    // tokens per expert (T/E = 32768/32)

// Tile config
#define BM 128
#define BN 128
#define BK 64

typedef __attribute__((ext_vector_type(8))) __bf16 bf16x8;
typedef __attribute__((ext_vector_type(4))) float  f32x4;

__device__ __forceinline__ __bf16 f2b(float f) { return (__bf16)f; }

__device__ __forceinline__ bf16x8 pack8(const f32x4 a, const f32x4 b) {
  bf16x8 v;
  v[0] = f2b(a[0]); v[1] = f2b(a[1]); v[2] = f2b(a[2]); v[3] = f2b(a[3]);
  v[4] = f2b(b[0]); v[5] = f2b(b[1]); v[6] = f2b(b[2]); v[7] = f2b(b[3]);
  return v;
}

// ---------------------------------------------------------------------------
// Kernel 1: gate_up = x_e @ w13_e ; h = silu(gate)*up  (bf16 out to ws)
// 512 threads = 8 waves in 2x4 grid; each wave owns 64x32 of BOTH gate and up
// (acc = 64 f32 -> prefetch regs fit, no spill; SwiGLU fused in-wave).
// Staging: waves 0-3 stage Bg, waves 4-7 stage Bu; A spread over all 512.
// T14 pipeline: cvt+ds_write -> barrier -> issue next loads -> MFMA(prio=1)
// -> lgkmcnt(0)+s_barrier (prefetch loads stay in flight across barrier).
// LDS XOR swizzle (R2/R3 counter-verified):
//   A:  As[row][(oct ^ (row&7))*8 + j]
//   B:  Bg/Bu[row][(oct ^ ((row>>1)&7))*8 + j]
// ---------------------------------------------------------------------------
__global__ __launch_bounds__(512, 2)
void moe_gemm1_swiglu(const float* __restrict__ x,
                      const float* __restrict__ w13,
                      __bf16* __restrict__ h) {
  __shared__ __bf16 As[BM][BK];
  __shared__ __bf16 Bg[BN][BK];
  __shared__ __bf16 Bu[BN][BK];

  const int t  = threadIdx.x;
  const int e  = blockIdx.z;
  const int m0 = blockIdx.y * BM;
  const int n0 = blockIdx.x * BN;

  const float* xA = x   + (size_t)(e * GT + m0) * HD;
  const float* wB = w13 + (size_t)e * HD * (2 * ID);

  const int wid = t >> 6, lane = t & 63;
  const int wm = wid >> 2, wn = wid & 3;   // 2x4 wave grid: 64 rows x 32 cols
  const int fr = lane & 15, fq = lane >> 4;

  // B staging ownership: threads 0-255 stage Bg, 256-511 stage Bu (wave-uniform)
  const int tm = t & 255;
  const int nq = tm & 31;        // n-quad (4 cols)
  const int ko = tm >> 5;        // k-octet (8 k-rows)
  const int bcol = (t < 256 ? 0 : ID) + n0 + nq * 4;
  __bf16 (*Bmine)[BK] = (t < 256) ? Bg : Bu;

  f32x4 accg[4][2];
  f32x4 accu[4][2];
#pragma unroll
  for (int i = 0; i < 4; ++i)
#pragma unroll
    for (int j = 0; j < 2; ++j) { accg[i][j] = 0.f; accu[i][j] = 0.f; }

  // prefetch registers: A 16 + B 32 = 48 VGPRs
  f32x4 ra[2][2];
  f32x4 rb[8];

#define LOAD_TILE1(K0)                                                         \
  do {                                                                         \
    _Pragma("unroll")                                                          \
    for (int i = 0; i < 2; ++i) {                                              \
      int id = i * 512 + t;                                                    \
      int r = id >> 3, oc = id & 7;                                            \
      const float* src = xA + (size_t)r * HD + (K0) + oc * 8;                  \
      ra[i][0] = *reinterpret_cast<const f32x4*>(src);                         \
      ra[i][1] = *reinterpret_cast<const f32x4*>(src + 4);                     \
    }                                                                          \
    const float* pb = wB + (size_t)((K0) + ko * 8) * (2 * ID) + bcol;          \
    _Pragma("unroll")                                                          \
    for (int j = 0; j < 8; ++j)                                                \
      rb[j] = *reinterpret_cast<const f32x4*>(pb + (size_t)j * (2 * ID));      \
  } while (0)

  LOAD_TILE1(0);

  for (int k0 = 0; k0 < HD; k0 += BK) {
    // ---- cvt + ds_write from prefetched regs ----
#pragma unroll
    for (int i = 0; i < 2; ++i) {
      int id = i * 512 + t;
      int r = id >> 3, oc = id & 7;
      *reinterpret_cast<bf16x8*>(&As[r][(oc ^ (r & 7)) * 8]) = pack8(ra[i][0], ra[i][1]);
    }
#pragma unroll
    for (int c = 0; c < 4; ++c) {
      int row = nq * 4 + c;
      int slot = (ko ^ ((row >> 1) & 7)) * 8;
      bf16x8 v;
#pragma unroll
      for (int j = 0; j < 8; ++j) v[j] = f2b(rb[j][c]);
      *reinterpret_cast<bf16x8*>(&Bmine[row][slot]) = v;
    }
    __syncthreads();

    // ---- issue next tile's global loads (latency hides under MFMA) ----
    if (k0 + BK < HD) LOAD_TILE1(k0 + BK);

    // ---- MFMA on tile k0 ----
    __builtin_amdgcn_s_setprio(1);
#pragma unroll
    for (int kk = 0; kk < BK; kk += 32) {
      const int kb = kk >> 3;   // 0 or 4
      bf16x8 af[4], bgf[2], buf2[2];
#pragma unroll
      for (int mi = 0; mi < 4; ++mi) {
        int row = wm * 64 + mi * 16 + fr;
        int oct = (fq + kb) ^ (row & 7);
        af[mi] = *reinterpret_cast<const bf16x8*>(&As[row][oct * 8]);
      }
#pragma unroll
      for (int ni = 0; ni < 2; ++ni) {
        int row = wn * 32 + ni * 16 + fr;
        int oct = (fq + kb) ^ ((row >> 1) & 7);
        bgf[ni]  = *reinterpret_cast<const bf16x8*>(&Bg[row][oct * 8]);
        buf2[ni] = *reinterpret_cast<const bf16x8*>(&Bu[row][oct * 8]);
      }
#pragma unroll
      for (int mi = 0; mi < 4; ++mi)
#pragma unroll
        for (int ni = 0; ni < 2; ++ni) {
          accg[mi][ni] = __builtin_amdgcn_mfma_f32_16x16x32_bf16(af[mi], bgf[ni], accg[mi][ni], 0, 0, 0);
          accu[mi][ni] = __builtin_amdgcn_mfma_f32_16x16x32_bf16(af[mi], buf2[ni], accu[mi][ni], 0, 0, 0);
        }
    }
    __builtin_amdgcn_s_setprio(0);

    // ---- tail barrier WITHOUT vmcnt drain ----
    asm volatile("s_waitcnt lgkmcnt(0)" ::: "memory");
    __builtin_amdgcn_s_barrier();
  }
#undef LOAD_TILE1

  // ---- epilogue: SwiGLU (in-wave), write h (bf16) ----
#pragma unroll
  for (int mi = 0; mi < 4; ++mi)
#pragma unroll
    for (int ni = 0; ni < 2; ++ni)
#pragma unroll
      for (int j = 0; j < 4; ++j) {
        int row = m0 + wm * 64 + mi * 16 + fq * 4 + j;
        int col = n0 + wn * 32 + ni * 16 + fr;
        float g = accg[mi][ni][j];
        float u = accu[mi][ni][j];
        float s = g / (1.f + __expf(-g));
        h[(size_t)(e * GT + row) * ID + col] = f2b(s * u);
      }
}

// ---------------------------------------------------------------------------
// Kernel 2: out = h @ w2_e   (h bf16 [T][I], w2 f32 [E][I][H], out f32)
// grid (HD/BN=16, GT/BM=8, NE=32), 256 threads. T14 pipeline (R4, proven).
// ---------------------------------------------------------------------------
__global__ __launch_bounds__(256, 2)
void moe_gemm2(const __bf16* __restrict__ h,
               const float* __restrict__ w2,
               float* __restrict__ out) {
  __shared__ __bf16 As[BM][BK];
  __shared__ __bf16 Bs[BN][BK];

  const int t  = threadIdx.x;
  const int e  = blockIdx.z;
  const int m0 = blockIdx.y * BM;
  const int n0 = blockIdx.x * BN;

  const __bf16* hA = h  + (size_t)(e * GT + m0) * ID;
  const float*  wB = w2 + (size_t)e * ID * HD;

  const int wid = t >> 6, lane = t & 63;
  const int wm = wid >> 1, wn = wid & 1;
  const int fr = lane & 15, fq = lane >> 4;

  const int nq = t & 31;
  const int ko = t >> 5;

  f32x4 acc[4][4];
#pragma unroll
  for (int i = 0; i < 4; ++i)
#pragma unroll
    for (int j = 0; j < 4; ++j) acc[i][j] = 0.f;

  bf16x8 raa[4];
  f32x4 rb[8];

#define LOAD_TILE2(K0)                                                         \
  do {                                                                         \
    _Pragma("unroll")                                                          \
    for (int i = 0; i < 4; ++i) {                                              \
      int id = i * 256 + t;                                                    \
      int koA = id & 7, m = id >> 3;                                           \
      raa[i] = *reinterpret_cast<const bf16x8*>(hA + (size_t)m * ID + (K0) + koA * 8); \
    }                                                                          \
    const float* pg = wB + (size_t)((K0) + ko * 8) * HD + (n0 + nq * 4);       \
    _Pragma("unroll")                                                          \
    for (int j = 0; j < 8; ++j)                                                \
      rb[j] = *reinterpret_cast<const f32x4*>(pg + (size_t)j * HD);            \
  } while (0)

  LOAD_TILE2(0);

  for (int k0 = 0; k0 < ID; k0 += BK) {
    // ---- ds_write from regs ----
#pragma unroll
    for (int i = 0; i < 4; ++i) {
      int id = i * 256 + t;
      int koA = id & 7, m = id >> 3;
      *reinterpret_cast<bf16x8*>(&As[m][(koA ^ (m & 7)) * 8]) = raa[i];
    }
#pragma unroll
    for (int c = 0; c < 4; ++c) {
      int row = nq * 4 + c;
      int slot = (ko ^ ((row >> 1) & 7)) * 8;
      bf16x8 v;
#pragma unroll
      for (int j = 0; j < 8; ++j) v[j] = f2b(rb[j][c]);
      *reinterpret_cast<bf16x8*>(&Bs[row][slot]) = v;
    }
    __syncthreads();

    // ---- issue next tile's loads ----
    if (k0 + BK < ID) LOAD_TILE2(k0 + BK);

    // ---- MFMA ----
    __builtin_amdgcn_s_setprio(1);
#pragma unroll
    for (int kk = 0; kk < BK; kk += 32) {
      const int kb = kk >> 3;
      bf16x8 af[4], bf[4];
#pragma unroll
      for (int mi = 0; mi < 4; ++mi) {
        int row = wm * 64 + mi * 16 + fr;
        int oct = (fq + kb) ^ (row & 7);
        af[mi] = *reinterpret_cast<const bf16x8*>(&As[row][oct * 8]);
      }
#pragma unroll
      for (int ni = 0; ni < 4; ++ni) {
        int row = wn * 64 + ni * 16 + fr;
        int oct = (fq + kb) ^ ((row >> 1) & 7);
        bf[ni] = *reinterpret_cast<const bf16x8*>(&Bs[row][oct * 8]);
      }
#pragma unroll
      for (int mi = 0; mi < 4; ++mi)
#pragma unroll
        for (int ni = 0; ni < 4; ++ni)
          acc[mi][ni] = __builtin_amdgcn_mfma_f32_16x16x32_bf16(af[mi], bf[ni], acc[mi][ni], 0, 0, 0);
    }
    __builtin_amdgcn_s_setprio(0);

    asm volatile("s_waitcnt lgkmcnt(0)" ::: "memory");
    __builtin_amdgcn_s_barrier();
  }
#undef LOAD_TILE2

  // ---- epilogue: f32 store ----
#pragma unroll
  for (int mi = 0; mi < 4; ++mi)
#pragma unroll
    for (int ni = 0; ni < 4; ++ni)
#pragma unroll
      for (int j = 0; j < 4; ++j) {
        int row = m0 + wm * 64 + mi * 16 + fq * 4 + j;
        int col = n0 + wn * 64 + ni * 16 + fr;
        out[(size_t)(e * GT + row) * HD + col] = acc[mi][ni][j];
      }
}

extern "C" void kernel_launch(void* const* d_in, const int* in_sizes, int n_in,
                              void* d_out, int out_size, void* d_ws, size_t ws_size,
                              hipStream_t stream) {
  const float* x   = (const float*)d_in[0];
  const float* w13 = (const float*)d_in[1];
  const float* w2  = (const float*)d_in[2];
  float* out = (float*)d_out;
  __bf16* h = (__bf16*)d_ws;   // T x I bf16 = 64 MiB scratch

  moe_gemm1_swiglu<<<dim3(ID / BN, GT / BM, NE), dim3(512), 0, stream>>>(x, w13, h);
  moe_gemm2<<<dim3(HD / BN, GT / BM, NE), dim3(256), 0, stream>>>(h, w2, out);
}

// Round 6
// 734.830 us; speedup vs baseline: 2.2670x; 1.1224x over previous
//
#include <hip/hip_runtime.h>
#include <hip/hip_bf16.h>

// Problem constants (MoE grouped FFN, uniform groups)
#define NE 32      // experts
#define HD 2048    // hidden
#define ID 1024    // intermediate
#define GT 1024    // tokens per expert (T/E = 32768/32)

#define BK 64

typedef __attribute__((ext_vector_type(8))) __bf16 bf16x8;
typedef __attribute__((ext_vector_type(4))) float  f32x4;

__device__ __forceinline__ __bf16 f2b(float f) { return (__bf16)f; }

__device__ __forceinline__ bf16x8 pack8(const f32x4 a, const f32x4 b) {
  bf16x8 v;
  v[0] = f2b(a[0]); v[1] = f2b(a[1]); v[2] = f2b(a[2]); v[3] = f2b(a[3]);
  v[4] = f2b(b[0]); v[5] = f2b(b[1]); v[6] = f2b(b[2]); v[7] = f2b(b[3]);
  return v;
}

// ---------------------------------------------------------------------------
// Kernel 1: gate_up = x_e @ w13_e ; h = silu(gate)*up  (bf16 out to ws)
// BM=128, BN=64 (gate & up each 64 wide). 256 threads = 4 waves (2x2);
// each wave owns 64x32 of BOTH gate and up -> acc = 64 f32 (gemm2's proven
// register shape; prefetch 64 regs, no spill at launch_bounds(256,2)).
// Staging: waves 0-1 stage Bg, waves 2-3 stage Bu; A over all 256 threads.
// T14 pipeline (R4/R5-proven on gemm2): cvt+ds_write -> barrier -> issue
// next tile's loads -> MFMA(prio=1) -> lgkmcnt(0)+s_barrier (no vmcnt drain).
// LDS XOR swizzle (R2/R3 counter-verified):
//   A:  As[row][(oct ^ (row&7))*8 + j]
//   B:  Bg/Bu[row][(oct ^ ((row>>1)&7))*8 + j]
// ---------------------------------------------------------------------------
__global__ __launch_bounds__(256, 2)
void moe_gemm1_swiglu(const float* __restrict__ x,
                      const float* __restrict__ w13,
                      __bf16* __restrict__ h) {
  __shared__ __bf16 As[128][BK];
  __shared__ __bf16 Bg[64][BK];
  __shared__ __bf16 Bu[64][BK];

  const int t  = threadIdx.x;
  const int e  = blockIdx.z;
  const int m0 = blockIdx.y * 128;
  const int n0 = blockIdx.x * 64;

  const float* xA = x   + (size_t)(e * GT + m0) * HD;
  const float* wB = w13 + (size_t)e * HD * (2 * ID);

  const int wid = t >> 6, lane = t & 63;
  const int wm = wid >> 1, wn = wid & 1;   // 2x2 waves: 64 rows x 32 cols each
  const int fr = lane & 15, fq = lane >> 4;

  // B staging ownership: threads 0-127 stage Bg, 128-255 stage Bu
  const int tb = t & 127;
  const int nq = tb & 15;        // n-quad 0..15 (4 cols over 64)
  const int ko = tb >> 4;        // k-octet 0..7 (8 k-rows)
  const int bcol = (t < 128 ? 0 : ID) + n0 + nq * 4;
  __bf16 (*Bmine)[BK] = (t < 128) ? Bg : Bu;

  f32x4 accg[4][2];
  f32x4 accu[4][2];
#pragma unroll
  for (int i = 0; i < 4; ++i)
#pragma unroll
    for (int j = 0; j < 2; ++j) { accg[i][j] = 0.f; accu[i][j] = 0.f; }

  // prefetch registers: A 32 + B 32 = 64 VGPRs
  f32x4 ra[4][2];
  f32x4 rb[8];

#define LOAD_TILE1(K0)                                                         \
  do {                                                                         \
    _Pragma("unroll")                                                          \
    for (int i = 0; i < 4; ++i) {                                              \
      int id = i * 256 + t;                                                    \
      int r = id >> 3, oc = id & 7;                                            \
      const float* src = xA + (size_t)r * HD + (K0) + oc * 8;                  \
      ra[i][0] = *reinterpret_cast<const f32x4*>(src);                         \
      ra[i][1] = *reinterpret_cast<const f32x4*>(src + 4);                     \
    }                                                                          \
    const float* pb = wB + (size_t)((K0) + ko * 8) * (2 * ID) + bcol;          \
    _Pragma("unroll")                                                          \
    for (int j = 0; j < 8; ++j)                                                \
      rb[j] = *reinterpret_cast<const f32x4*>(pb + (size_t)j * (2 * ID));      \
  } while (0)

  LOAD_TILE1(0);

  for (int k0 = 0; k0 < HD; k0 += BK) {
    // ---- cvt + ds_write from prefetched regs ----
#pragma unroll
    for (int i = 0; i < 4; ++i) {
      int id = i * 256 + t;
      int r = id >> 3, oc = id & 7;
      *reinterpret_cast<bf16x8*>(&As[r][(oc ^ (r & 7)) * 8]) = pack8(ra[i][0], ra[i][1]);
    }
#pragma unroll
    for (int c = 0; c < 4; ++c) {
      int row = nq * 4 + c;
      int slot = (ko ^ ((row >> 1) & 7)) * 8;
      bf16x8 v;
#pragma unroll
      for (int j = 0; j < 8; ++j) v[j] = f2b(rb[j][c]);
      *reinterpret_cast<bf16x8*>(&Bmine[row][slot]) = v;
    }
    __syncthreads();

    // ---- issue next tile's global loads (latency hides under MFMA) ----
    if (k0 + BK < HD) LOAD_TILE1(k0 + BK);

    // ---- MFMA on tile k0 ----
    __builtin_amdgcn_s_setprio(1);
#pragma unroll
    for (int kk = 0; kk < BK; kk += 32) {
      const int kb = kk >> 3;   // 0 or 4
      bf16x8 af[4], bgf[2], buf2[2];
#pragma unroll
      for (int mi = 0; mi < 4; ++mi) {
        int row = wm * 64 + mi * 16 + fr;
        int oct = (fq + kb) ^ (row & 7);
        af[mi] = *reinterpret_cast<const bf16x8*>(&As[row][oct * 8]);
      }
#pragma unroll
      for (int ni = 0; ni < 2; ++ni) {
        int row = wn * 32 + ni * 16 + fr;
        int oct = (fq + kb) ^ ((row >> 1) & 7);
        bgf[ni]  = *reinterpret_cast<const bf16x8*>(&Bg[row][oct * 8]);
        buf2[ni] = *reinterpret_cast<const bf16x8*>(&Bu[row][oct * 8]);
      }
#pragma unroll
      for (int mi = 0; mi < 4; ++mi)
#pragma unroll
        for (int ni = 0; ni < 2; ++ni) {
          accg[mi][ni] = __builtin_amdgcn_mfma_f32_16x16x32_bf16(af[mi], bgf[ni], accg[mi][ni], 0, 0, 0);
          accu[mi][ni] = __builtin_amdgcn_mfma_f32_16x16x32_bf16(af[mi], buf2[ni], accu[mi][ni], 0, 0, 0);
        }
    }
    __builtin_amdgcn_s_setprio(0);

    // ---- tail barrier WITHOUT vmcnt drain ----
    asm volatile("s_waitcnt lgkmcnt(0)" ::: "memory");
    __builtin_amdgcn_s_barrier();
  }
#undef LOAD_TILE1

  // ---- epilogue: SwiGLU (in-wave), write h (bf16) ----
#pragma unroll
  for (int mi = 0; mi < 4; ++mi)
#pragma unroll
    for (int ni = 0; ni < 2; ++ni)
#pragma unroll
      for (int j = 0; j < 4; ++j) {
        int row = m0 + wm * 64 + mi * 16 + fq * 4 + j;
        int col = n0 + wn * 32 + ni * 16 + fr;
        float g = accg[mi][ni][j];
        float u = accu[mi][ni][j];
        float s = g / (1.f + __expf(-g));
        h[(size_t)(e * GT + row) * ID + col] = f2b(s * u);
      }
}

// ---------------------------------------------------------------------------
// Kernel 2: out = h @ w2_e   (h bf16 [T][I], w2 f32 [E][I][H], out f32)
// grid (HD/128=16, GT/128=8, NE=32), 256 threads. T14 pipeline (R4, proven).
// ---------------------------------------------------------------------------
__global__ __launch_bounds__(256, 2)
void moe_gemm2(const __bf16* __restrict__ h,
               const float* __restrict__ w2,
               float* __restrict__ out) {
  __shared__ __bf16 As[128][BK];
  __shared__ __bf16 Bs[128][BK];

  const int t  = threadIdx.x;
  const int e  = blockIdx.z;
  const int m0 = blockIdx.y * 128;
  const int n0 = blockIdx.x * 128;

  const __bf16* hA = h  + (size_t)(e * GT + m0) * ID;
  const float*  wB = w2 + (size_t)e * ID * HD;

  const int wid = t >> 6, lane = t & 63;
  const int wm = wid >> 1, wn = wid & 1;
  const int fr = lane & 15, fq = lane >> 4;

  const int nq = t & 31;
  const int ko = t >> 5;

  f32x4 acc[4][4];
#pragma unroll
  for (int i = 0; i < 4; ++i)
#pragma unroll
    for (int j = 0; j < 4; ++j) acc[i][j] = 0.f;

  bf16x8 raa[4];
  f32x4 rb[8];

#define LOAD_TILE2(K0)                                                         \
  do {                                                                         \
    _Pragma("unroll")                                                          \
    for (int i = 0; i < 4; ++i) {                                              \
      int id = i * 256 + t;                                                    \
      int koA = id & 7, m = id >> 3;                                           \
      raa[i] = *reinterpret_cast<const bf16x8*>(hA + (size_t)m * ID + (K0) + koA * 8); \
    }                                                                          \
    const float* pg = wB + (size_t)((K0) + ko * 8) * HD + (n0 + nq * 4);       \
    _Pragma("unroll")                                                          \
    for (int j = 0; j < 8; ++j)                                                \
      rb[j] = *reinterpret_cast<const f32x4*>(pg + (size_t)j * HD);            \
  } while (0)

  LOAD_TILE2(0);

  for (int k0 = 0; k0 < ID; k0 += BK) {
    // ---- ds_write from regs ----
#pragma unroll
    for (int i = 0; i < 4; ++i) {
      int id = i * 256 + t;
      int koA = id & 7, m = id >> 3;
      *reinterpret_cast<bf16x8*>(&As[m][(koA ^ (m & 7)) * 8]) = raa[i];
    }
#pragma unroll
    for (int c = 0; c < 4; ++c) {
      int row = nq * 4 + c;
      int slot = (ko ^ ((row >> 1) & 7)) * 8;
      bf16x8 v;
#pragma unroll
      for (int j = 0; j < 8; ++j) v[j] = f2b(rb[j][c]);
      *reinterpret_cast<bf16x8*>(&Bs[row][slot]) = v;
    }
    __syncthreads();

    // ---- issue next tile's loads ----
    if (k0 + BK < ID) LOAD_TILE2(k0 + BK);

    // ---- MFMA ----
    __builtin_amdgcn_s_setprio(1);
#pragma unroll
    for (int kk = 0; kk < BK; kk += 32) {
      const int kb = kk >> 3;
      bf16x8 af[4], bf[4];
#pragma unroll
      for (int mi = 0; mi < 4; ++mi) {
        int row = wm * 64 + mi * 16 + fr;
        int oct = (fq + kb) ^ (row & 7);
        af[mi] = *reinterpret_cast<const bf16x8*>(&As[row][oct * 8]);
      }
#pragma unroll
      for (int ni = 0; ni < 4; ++ni) {
        int row = wn * 64 + ni * 16 + fr;
        int oct = (fq + kb) ^ ((row >> 1) & 7);
        bf[ni] = *reinterpret_cast<const bf16x8*>(&Bs[row][oct * 8]);
      }
#pragma unroll
      for (int mi = 0; mi < 4; ++mi)
#pragma unroll
        for (int ni = 0; ni < 4; ++ni)
          acc[mi][ni] = __builtin_amdgcn_mfma_f32_16x16x32_bf16(af[mi], bf[ni], acc[mi][ni], 0, 0, 0);
    }
    __builtin_amdgcn_s_setprio(0);

    asm volatile("s_waitcnt lgkmcnt(0)" ::: "memory");
    __builtin_amdgcn_s_barrier();
  }
#undef LOAD_TILE2

  // ---- epilogue: f32 store ----
#pragma unroll
  for (int mi = 0; mi < 4; ++mi)
#pragma unroll
    for (int ni = 0; ni < 4; ++ni)
#pragma unroll
      for (int j = 0; j < 4; ++j) {
        int row = m0 + wm * 64 + mi * 16 + fq * 4 + j;
        int col = n0 + wn * 64 + ni * 16 + fr;
        out[(size_t)(e * GT + row) * HD + col] = acc[mi][ni][j];
      }
}

extern "C" void kernel_launch(void* const* d_in, const int* in_sizes, int n_in,
                              void* d_out, int out_size, void* d_ws, size_t ws_size,
                              hipStream_t stream) {
  const float* x   = (const float*)d_in[0];
  const float* w13 = (const float*)d_in[1];
  const float* w2  = (const float*)d_in[2];
  float* out = (float*)d_out;
  __bf16* h = (__bf16*)d_ws;   // T x I bf16 = 64 MiB scratch

  moe_gemm1_swiglu<<<dim3(ID / 64, GT / 128, NE), dim3(256), 0, stream>>>(x, w13, h);
  moe_gemm2<<<dim3(HD / 128, GT / 128, NE), dim3(256), 0, stream>>>(h, w2, out);
}